// Round 6
// baseline (398.337 us; speedup 1.0000x reference)
//
#include <hip/hip_runtime.h>
#include <math.h>

#define S 4096
#define H 32
#define D 128
#define IMP 4
#define RECENT 512
#define KEEP (IMP + RECENT)      // 516
#define SELECT (S - RECENT)      // 3584
#define S4 (S / 4)               // 1024 float4 per row

#define RCHUNKS 256
#define ROWS_TOTAL (H * S)                 // 131072
#define ROWS_PER (ROWS_TOTAL / RCHUNKS)    // 512  (compile-time)

typedef __attribute__((ext_vector_type(4))) float f4;

// ---------------- Kernel 1: partial column sums, reg-pipelined --------------
// grid (4, RCHUNKS), block 256. Same 8-deep register pipeline as R5; only the
// grid is doubled (4 blocks/CU -> 4 waves/SIMD) with ROWS_PER halved, both
// compile-time.
__global__ __launch_bounds__(256) void colsum_partial(const float* __restrict__ attn,
                                                      float* __restrict__ partials) {
    const int jc  = blockIdx.x;            // 0..3
    const int rc  = blockIdx.y;            // 0..RCHUNKS-1
    const int tid = threadIdx.x;           // 0..255
    const int j4  = jc * 256 + tid;        // float4 column index 0..1023

    const f4* p = reinterpret_cast<const f4*>(attn)
                + (size_t)rc * ROWS_PER * S4 + j4;

    f4 v0,v1,v2,v3,v4,v5,v6,v7;
    f4 acc0 = (f4)0.f, acc1 = (f4)0.f;

    v0 = p[(size_t)0 * S4]; v1 = p[(size_t)1 * S4];
    v2 = p[(size_t)2 * S4]; v3 = p[(size_t)3 * S4];
    v4 = p[(size_t)4 * S4]; v5 = p[(size_t)5 * S4];
    v6 = p[(size_t)6 * S4]; v7 = p[(size_t)7 * S4];

    for (int r = 8; r < ROWS_PER; r += 8) {
        const f4* q = p + (size_t)r * S4;
        f4 w0 = q[(size_t)0 * S4]; f4 w1 = q[(size_t)1 * S4];
        f4 w2 = q[(size_t)2 * S4]; f4 w3 = q[(size_t)3 * S4];
        f4 w4 = q[(size_t)4 * S4]; f4 w5 = q[(size_t)5 * S4];
        f4 w6 = q[(size_t)6 * S4]; f4 w7 = q[(size_t)7 * S4];
        acc0 += v0; acc1 += v1; acc0 += v2; acc1 += v3;
        acc0 += v4; acc1 += v5; acc0 += v6; acc1 += v7;
        v0 = w0; v1 = w1; v2 = w2; v3 = w3;
        v4 = w4; v5 = w5; v6 = w6; v7 = w7;
    }
    acc0 += v0; acc1 += v1; acc0 += v2; acc1 += v3;
    acc0 += v4; acc1 += v5; acc0 += v6; acc1 += v7;

    reinterpret_cast<f4*>(partials)[(size_t)rc * S4 + j4] = acc0 + acc1;
}

// ---------------- Kernel 2: reduce partials -> imp_score (mean over heads) --
__global__ __launch_bounds__(256) void reduce_partials(const float* __restrict__ partials,
                                                       float* __restrict__ imp) {
    const int j = blockIdx.x * 256 + threadIdx.x;   // 0..4095
    float s = 0.f;
    #pragma unroll 8
    for (int rc = 0; rc < RCHUNKS; ++rc) s += partials[(size_t)rc * S + j];
    imp[j] = s * (1.0f / (float)H);
}

// ---------------- Kernel 3: single-pass top-4 + small outputs ---------------
__global__ __launch_bounds__(256) void topk_and_small(const float* __restrict__ imp,
                                                      int* __restrict__ keep_idx,
                                                      float* __restrict__ imp_out,
                                                      float* __restrict__ counter_out) {
    __shared__ float sv[256 * IMP];
    __shared__ int   si[256 * IMP];
    const int tid = threadIdx.x;

    float av[IMP]; int ai[IMP];
    for (int k = 0; k < IMP; ++k) { av[k] = -INFINITY; ai[k] = 0x7fffffff; }
    for (int i = 0; i < SELECT / 256; ++i) {
        const int j = tid + 256 * i;
        const float v = imp[j];
        int pos = IMP;
        for (int k = IMP - 1; k >= 0; --k) {
            if (v > av[k] || (v == av[k] && j < ai[k])) pos = k;
        }
        if (pos < IMP) {
            for (int k = IMP - 1; k > pos; --k) { av[k] = av[k-1]; ai[k] = ai[k-1]; }
            av[pos] = v; ai[pos] = j;
        }
    }
    for (int k = 0; k < IMP; ++k) { sv[tid * IMP + k] = av[k]; si[tid * IMP + k] = ai[k]; }
    __syncthreads();

    for (int off = 128; off > 0; off >>= 1) {
        if (tid < off) {
            float bv[IMP]; int bi[IMP];
            for (int k = 0; k < IMP; ++k) {
                av[k] = sv[tid * IMP + k];         ai[k] = si[tid * IMP + k];
                bv[k] = sv[(tid + off) * IMP + k]; bi[k] = si[(tid + off) * IMP + k];
            }
            float rv[IMP]; int ri[IMP];
            int x = 0, y = 0;
            for (int o = 0; o < IMP; ++o) {
                bool takeA = (y >= IMP) ||
                             (x < IMP && (av[x] > bv[y] || (av[x] == bv[y] && ai[x] < bi[y])));
                if (takeA) { rv[o] = av[x]; ri[o] = ai[x]; ++x; }
                else       { rv[o] = bv[y]; ri[o] = bi[y]; ++y; }
            }
            for (int k = 0; k < IMP; ++k) { sv[tid * IMP + k] = rv[k]; si[tid * IMP + k] = ri[k]; }
        }
        __syncthreads();
    }

    __shared__ int chosen[IMP];
    if (tid == 0) {
        int c[IMP];
        for (int k = 0; k < IMP; ++k) c[k] = si[k];
        for (int a = 0; a < IMP; ++a)
            for (int b2 = a + 1; b2 < IMP; ++b2)
                if (c[b2] < c[a]) { int t2 = c[a]; c[a] = c[b2]; c[b2] = t2; }
        for (int k = 0; k < IMP; ++k) chosen[k] = c[k];
    }
    __syncthreads();

    for (int n = tid; n < KEEP; n += 256) {
        const int j = (n < IMP) ? chosen[n] : (SELECT + (n - IMP));
        keep_idx[n]    = j;
        imp_out[n]     = imp[j];
        counter_out[n] = (float)(S - j);
    }
}

// ---------------- Kernel 4: gather K/V rows ---------------------------------
__global__ __launch_bounds__(256) void gather_kv(const float* __restrict__ k_cache,
                                                 const float* __restrict__ v_cache,
                                                 const int* __restrict__ keep_idx,
                                                 float* __restrict__ out) {
    const int PER = H * KEEP * (D / 4);          // 528384 float4 per tensor
    const int gid = blockIdx.x * 256 + threadIdx.x;
    if (gid >= 2 * PER) return;

    const int which = gid / PER;                 // 0 = K, 1 = V
    int rem = gid - which * PER;
    const int h  = rem / (KEEP * (D / 4));
    rem -= h * (KEEP * (D / 4));
    const int n  = rem / (D / 4);
    const int d4 = rem - n * (D / 4);

    const int row = keep_idx[n];
    const float* src = which ? v_cache : k_cache;
    f4 v = reinterpret_cast<const f4*>(src)[((size_t)h * S + row) * (D / 4) + d4];
    reinterpret_cast<f4*>(out)[(size_t)which * PER + ((size_t)h * KEEP + n) * (D / 4) + d4] = v;
}

extern "C" void kernel_launch(void* const* d_in, const int* in_sizes, int n_in,
                              void* d_out, int out_size, void* d_ws, size_t ws_size,
                              hipStream_t stream) {
    const float* k_cache = (const float*)d_in[0];
    const float* v_cache = (const float*)d_in[1];
    const float* attn    = (const float*)d_in[2];
    float* out = (float*)d_out;

    // workspace: partials[RCHUNKS*S] | imp[S] | keep_idx[KEEP]
    float* partials = (float*)d_ws;
    float* imp      = partials + (size_t)RCHUNKS * S;
    int*   keep_idx = (int*)(imp + S);

    float* imp_out     = out + (size_t)2 * H * KEEP * D;
    float* counter_out = imp_out + KEEP;
    (void)in_sizes; (void)n_in; (void)out_size; (void)ws_size;

    colsum_partial<<<dim3(4, RCHUNKS), 256, 0, stream>>>(attn, partials);
    reduce_partials<<<dim3(S / 256), 256, 0, stream>>>(partials, imp);
    topk_and_small<<<1, 256, 0, stream>>>(imp, keep_idx, imp_out, counter_out);
    gather_kv<<<dim3((2 * H * KEEP * (D / 4) + 255) / 256), 256, 0, stream>>>(k_cache, v_cache, keep_idx, out);
}

// Round 7
// 385.296 us; speedup vs baseline: 1.0338x; 1.0338x over previous
//
#include <hip/hip_runtime.h>
#include <math.h>

#define S 4096
#define H 32
#define D 128
#define IMP 4
#define RECENT 512
#define KEEP (IMP + RECENT)      // 516
#define SELECT (S - RECENT)      // 3584
#define S4 (S / 4)               // 1024 float4 per row

#define RCHUNKS 128
#define ROWS_TOTAL (H * S)                 // 131072
#define ROWS_PER (ROWS_TOTAL / RCHUNKS)    // 1024  (compile-time)

typedef __attribute__((ext_vector_type(4))) float f4;

// ---------------- Kernel 1: partial column sums, reg-pipelined --------------
// Final config (R5): grid (4,128) = 2 blocks/CU, 1024-row streams. The 8-deep
// register pipeline keeps >=8 loads in flight; longer streams beat higher
// occupancy (R6: 2x grid with 512-row streams regressed 13us — DRAM page
// locality dominates).
__global__ __launch_bounds__(256) void colsum_partial(const float* __restrict__ attn,
                                                      float* __restrict__ partials) {
    const int jc  = blockIdx.x;            // 0..3
    const int rc  = blockIdx.y;            // 0..127
    const int tid = threadIdx.x;           // 0..255
    const int j4  = jc * 256 + tid;        // float4 column index 0..1023

    const f4* p = reinterpret_cast<const f4*>(attn)
                + (size_t)rc * ROWS_PER * S4 + j4;

    f4 v0,v1,v2,v3,v4,v5,v6,v7;
    f4 acc0 = (f4)0.f, acc1 = (f4)0.f;

    v0 = p[(size_t)0 * S4]; v1 = p[(size_t)1 * S4];
    v2 = p[(size_t)2 * S4]; v3 = p[(size_t)3 * S4];
    v4 = p[(size_t)4 * S4]; v5 = p[(size_t)5 * S4];
    v6 = p[(size_t)6 * S4]; v7 = p[(size_t)7 * S4];

    for (int r = 8; r < ROWS_PER; r += 8) {
        const f4* q = p + (size_t)r * S4;
        f4 w0 = q[(size_t)0 * S4]; f4 w1 = q[(size_t)1 * S4];
        f4 w2 = q[(size_t)2 * S4]; f4 w3 = q[(size_t)3 * S4];
        f4 w4 = q[(size_t)4 * S4]; f4 w5 = q[(size_t)5 * S4];
        f4 w6 = q[(size_t)6 * S4]; f4 w7 = q[(size_t)7 * S4];
        acc0 += v0; acc1 += v1; acc0 += v2; acc1 += v3;
        acc0 += v4; acc1 += v5; acc0 += v6; acc1 += v7;
        v0 = w0; v1 = w1; v2 = w2; v3 = w3;
        v4 = w4; v5 = w5; v6 = w6; v7 = w7;
    }
    acc0 += v0; acc1 += v1; acc0 += v2; acc1 += v3;
    acc0 += v4; acc1 += v5; acc0 += v6; acc1 += v7;

    reinterpret_cast<f4*>(partials)[(size_t)rc * S4 + j4] = acc0 + acc1;
}

// ---------------- Kernel 2: reduce partials -> imp_score (mean over heads) --
__global__ __launch_bounds__(256) void reduce_partials(const float* __restrict__ partials,
                                                       float* __restrict__ imp) {
    const int j = blockIdx.x * 256 + threadIdx.x;   // 0..4095
    float s = 0.f;
    #pragma unroll 8
    for (int rc = 0; rc < RCHUNKS; ++rc) s += partials[(size_t)rc * S + j];
    imp[j] = s * (1.0f / (float)H);
}

// ---------------- Kernel 3: single-pass top-4 + small outputs ---------------
__global__ __launch_bounds__(256) void topk_and_small(const float* __restrict__ imp,
                                                      int* __restrict__ keep_idx,
                                                      float* __restrict__ imp_out,
                                                      float* __restrict__ counter_out) {
    __shared__ float sv[256 * IMP];
    __shared__ int   si[256 * IMP];
    const int tid = threadIdx.x;

    float av[IMP]; int ai[IMP];
    for (int k = 0; k < IMP; ++k) { av[k] = -INFINITY; ai[k] = 0x7fffffff; }
    for (int i = 0; i < SELECT / 256; ++i) {
        const int j = tid + 256 * i;
        const float v = imp[j];
        int pos = IMP;
        for (int k = IMP - 1; k >= 0; --k) {
            if (v > av[k] || (v == av[k] && j < ai[k])) pos = k;
        }
        if (pos < IMP) {
            for (int k = IMP - 1; k > pos; --k) { av[k] = av[k-1]; ai[k] = ai[k-1]; }
            av[pos] = v; ai[pos] = j;
        }
    }
    for (int k = 0; k < IMP; ++k) { sv[tid * IMP + k] = av[k]; si[tid * IMP + k] = ai[k]; }
    __syncthreads();

    for (int off = 128; off > 0; off >>= 1) {
        if (tid < off) {
            float bv[IMP]; int bi[IMP];
            for (int k = 0; k < IMP; ++k) {
                av[k] = sv[tid * IMP + k];         ai[k] = si[tid * IMP + k];
                bv[k] = sv[(tid + off) * IMP + k]; bi[k] = si[(tid + off) * IMP + k];
            }
            float rv[IMP]; int ri[IMP];
            int x = 0, y = 0;
            for (int o = 0; o < IMP; ++o) {
                bool takeA = (y >= IMP) ||
                             (x < IMP && (av[x] > bv[y] || (av[x] == bv[y] && ai[x] < bi[y])));
                if (takeA) { rv[o] = av[x]; ri[o] = ai[x]; ++x; }
                else       { rv[o] = bv[y]; ri[o] = bi[y]; ++y; }
            }
            for (int k = 0; k < IMP; ++k) { sv[tid * IMP + k] = rv[k]; si[tid * IMP + k] = ri[k]; }
        }
        __syncthreads();
    }

    __shared__ int chosen[IMP];
    if (tid == 0) {
        int c[IMP];
        for (int k = 0; k < IMP; ++k) c[k] = si[k];
        for (int a = 0; a < IMP; ++a)
            for (int b2 = a + 1; b2 < IMP; ++b2)
                if (c[b2] < c[a]) { int t2 = c[a]; c[a] = c[b2]; c[b2] = t2; }
        for (int k = 0; k < IMP; ++k) chosen[k] = c[k];
    }
    __syncthreads();

    for (int n = tid; n < KEEP; n += 256) {
        const int j = (n < IMP) ? chosen[n] : (SELECT + (n - IMP));
        keep_idx[n]    = j;
        imp_out[n]     = imp[j];
        counter_out[n] = (float)(S - j);
    }
}

// ---------------- Kernel 4: gather K/V rows ---------------------------------
__global__ __launch_bounds__(256) void gather_kv(const float* __restrict__ k_cache,
                                                 const float* __restrict__ v_cache,
                                                 const int* __restrict__ keep_idx,
                                                 float* __restrict__ out) {
    const int PER = H * KEEP * (D / 4);          // 528384 float4 per tensor
    const int gid = blockIdx.x * 256 + threadIdx.x;
    if (gid >= 2 * PER) return;

    const int which = gid / PER;                 // 0 = K, 1 = V
    int rem = gid - which * PER;
    const int h  = rem / (KEEP * (D / 4));
    rem -= h * (KEEP * (D / 4));
    const int n  = rem / (D / 4);
    const int d4 = rem - n * (D / 4);

    const int row = keep_idx[n];
    const float* src = which ? v_cache : k_cache;
    f4 v = reinterpret_cast<const f4*>(src)[((size_t)h * S + row) * (D / 4) + d4];
    reinterpret_cast<f4*>(out)[(size_t)which * PER + ((size_t)h * KEEP + n) * (D / 4) + d4] = v;
}

extern "C" void kernel_launch(void* const* d_in, const int* in_sizes, int n_in,
                              void* d_out, int out_size, void* d_ws, size_t ws_size,
                              hipStream_t stream) {
    const float* k_cache = (const float*)d_in[0];
    const float* v_cache = (const float*)d_in[1];
    const float* attn    = (const float*)d_in[2];
    float* out = (float*)d_out;

    // workspace: partials[RCHUNKS*S] | imp[S] | keep_idx[KEEP]
    float* partials = (float*)d_ws;
    float* imp      = partials + (size_t)RCHUNKS * S;
    int*   keep_idx = (int*)(imp + S);

    float* imp_out     = out + (size_t)2 * H * KEEP * D;
    float* counter_out = imp_out + KEEP;
    (void)in_sizes; (void)n_in; (void)out_size; (void)ws_size;

    colsum_partial<<<dim3(4, RCHUNKS), 256, 0, stream>>>(attn, partials);
    reduce_partials<<<dim3(S / 256), 256, 0, stream>>>(partials, imp);
    topk_and_small<<<1, 256, 0, stream>>>(imp, keep_idx, imp_out, counter_out);
    gather_kv<<<dim3((2 * H * KEEP * (D / 4) + 255) / 256), 256, 0, stream>>>(k_cache, v_cache, keep_idx, out);
}